// Round 1
// baseline (332.382 us; speedup 1.0000x reference)
//
#include <hip/hip_runtime.h>

#define BETA2 25.0f
#define EPS 1e-9f

// d_ws layout: 3 x unsigned int counters [tp, fp, fn]

__global__ void fbeta_zero(unsigned int* counts) {
    if (threadIdx.x < 3) counts[threadIdx.x] = 0u;
}

__global__ void __launch_bounds__(256) fbeta_count(const float4* __restrict__ t4,
                                                   const float4* __restrict__ l4,
                                                   unsigned int* __restrict__ counts,
                                                   int n4) {
    int tp = 0, fp = 0, fn = 0;
    const int stride = gridDim.x * blockDim.x;
    for (int i = blockIdx.x * blockDim.x + threadIdx.x; i < n4; i += stride) {
        float4 tv = t4[i];
        float4 lv = l4[i];
        {
            int tn = (tv.x != 0.0f), ln = (lv.x != 0.0f);
            tp += tn & ln; fp += tn & (ln ^ 1); fn += (tn ^ 1) & ln;
        }
        {
            int tn = (tv.y != 0.0f), ln = (lv.y != 0.0f);
            tp += tn & ln; fp += tn & (ln ^ 1); fn += (tn ^ 1) & ln;
        }
        {
            int tn = (tv.z != 0.0f), ln = (lv.z != 0.0f);
            tp += tn & ln; fp += tn & (ln ^ 1); fn += (tn ^ 1) & ln;
        }
        {
            int tn = (tv.w != 0.0f), ln = (lv.w != 0.0f);
            tp += tn & ln; fp += tn & (ln ^ 1); fn += (tn ^ 1) & ln;
        }
    }
    // wave-64 reduction
    #pragma unroll
    for (int off = 32; off > 0; off >>= 1) {
        tp += __shfl_down(tp, off, 64);
        fp += __shfl_down(fp, off, 64);
        fn += __shfl_down(fn, off, 64);
    }
    if ((threadIdx.x & 63) == 0) {
        atomicAdd(&counts[0], (unsigned int)tp);
        atomicAdd(&counts[1], (unsigned int)fp);
        atomicAdd(&counts[2], (unsigned int)fn);
    }
}

__global__ void fbeta_final(const unsigned int* __restrict__ counts,
                            float* __restrict__ out) {
    float tp = (float)counts[0] + EPS;
    float fp = (float)counts[1] + EPS;
    float fn = (float)counts[2] + EPS;
    float precision = tp / (tp + fp);
    float recall    = tp / (tp + fn);
    out[0] = (1.0f + BETA2) * (precision * recall) / (BETA2 * precision + recall);
}

extern "C" void kernel_launch(void* const* d_in, const int* in_sizes, int n_in,
                              void* d_out, int out_size, void* d_ws, size_t ws_size,
                              hipStream_t stream) {
    const float* targets = (const float*)d_in[0];
    const float* labels  = (const float*)d_in[1];
    float* out = (float*)d_out;
    unsigned int* counts = (unsigned int*)d_ws;

    const int n = in_sizes[0];      // 67108864, divisible by 4
    const int n4 = n >> 2;

    fbeta_zero<<<1, 64, 0, stream>>>(counts);

    const int block = 256;
    const int grid = 2048;          // 256 CU x 8 blocks, grid-stride covers rest
    fbeta_count<<<grid, block, 0, stream>>>((const float4*)targets,
                                            (const float4*)labels,
                                            counts, n4);

    fbeta_final<<<1, 1, 0, stream>>>(counts, out);
}